// Round 5
// baseline (131.308 us; speedup 1.0000x reference)
//
#include <hip/hip_runtime.h>

// ---------------------------------------------------------------------------
// BatchRelationalModule: b=16, c=64, L=256, F=64
// Round 11: 1-WAVE WORKGROUPS, ZERO LDS in k_main. r9 counters: k_main
// 41.4us, VALUBusy 36% (14.8us busy), MfmaUtil 23% (9.4us), Occupancy 17.3%
// (~1.4 waves/SIMD resident despite VGPR=92 allowing 5) => stall-bound with
// no TLP. r10's 2-chain ILP crashed (core dump, likely ICE/VGPR blowup) —
// reverted. This round decouples waves instead: 64-thr blocks, grid (256,16)
// = 4096 independent 1-wave workgroups (16/CU). B'-rows read directly from
// global (quad-broadcast ldf4, L1/L2-resident; Bg=1MB) with 1-ahead
// prefetch; no barriers, no staging. Part widened to one slot per wave
// ([16][256][64] = 4MB; ws=256MB per the poison-fill size). MFMA loops
// k-outer so the 4 acc chains per layer are explicitly independent.
// Predict: k_main -> 16-20us (VALU-busy floor), Occupancy >=40%.
// ---------------------------------------------------------------------------

typedef short s8v __attribute__((ext_vector_type(8)));   // 8 x bf16 (4 VGPR)
typedef short s4v __attribute__((ext_vector_type(4)));   // 4 x bf16 (2 VGPR)
typedef float f4v __attribute__((ext_vector_type(4)));   // 4 x f32  (4 VGPR)

#define KEEP(x) asm volatile("" : "+v"(x))   // opaque: forbids remat/sink

#define MFMA16(a, b, c) __builtin_amdgcn_mfma_f32_16x16x16bf16_1k(a, b, c, 0, 0, 0)
#define MFMA32(a, b, c) __builtin_amdgcn_mfma_f32_16x16x32_bf16(a, b, c, 0, 0, 0)

__device__ __forceinline__ short bfr(float v) {
  return __builtin_bit_cast(short, (__bf16)v);           // fp32 -> bf16 (RNE)
}
__device__ __forceinline__ f4v relu4(f4v v) {
  f4v z = {0.f, 0.f, 0.f, 0.f};
  return __builtin_elementwise_max(v, z);
}
__device__ __forceinline__ s8v cvt8(f4v a, f4v b) {
  s8v r;
  r[0] = bfr(a[0]); r[1] = bfr(a[1]); r[2] = bfr(a[2]); r[3] = bfr(a[3]);
  r[4] = bfr(b[0]); r[5] = bfr(b[1]); r[6] = bfr(b[2]); r[7] = bfr(b[3]);
  return r;
}
__device__ __forceinline__ s4v cvt4(f4v a) {
  s4v r;
  r[0] = bfr(a[0]); r[1] = bfr(a[1]); r[2] = bfr(a[2]); r[3] = bfr(a[3]);
  return r;
}
__device__ __forceinline__ f4v ldf4(const float* p) {
  return *(const f4v*)p;
}

// ---------------------------------------------------------------------------
// Kernel 1: precompute A and B' (fp32). Unchanged (verified).
// ---------------------------------------------------------------------------
__global__ __launch_bounds__(256) void k_pre(
    const float* __restrict__ x, const float* __restrict__ Wg0,
    const float* __restrict__ bg0, float* __restrict__ Ag,
    float* __restrict__ Bg) {
  __shared__ float ws[64 * 131];
  __shared__ float xs[64 * 17];

  const int t = threadIdx.x;
  const int b = blockIdx.x >> 4;
  const int l0 = (blockIdx.x & 15) * 16;

  for (int i = t; i < 64 * 130; i += 256) {
    int f = i / 130, d = i - f * 130;
    ws[f * 131 + d] = Wg0[i];
  }
  for (int i = t; i < 64 * 16; i += 256) {
    int ch = i >> 4, li = i & 15;
    xs[ch * 17 + li] = x[b * 16384 + ch * 256 + l0 + li];
  }
  __syncthreads();

  const int f = t & 63;
  const int w = t >> 6;
  float accA[4] = {0.f, 0.f, 0.f, 0.f};
  float accB[4] = {0.f, 0.f, 0.f, 0.f};
  for (int d = 0; d < 64; ++d) {
    float wa = ws[f * 131 + d];
    float wb = ws[f * 131 + 65 + d];
#pragma unroll
    for (int i = 0; i < 4; ++i) {
      float xv = xs[d * 17 + w + 4 * i];
      accA[i] += xv * wa;
      accB[i] += xv * wb;
    }
  }
  const float wca = ws[f * 131 + 64];
  const float wcb = ws[f * 131 + 129];
  const float bias = bg0[f];
#pragma unroll
  for (int i = 0; i < 4; ++i) {
    int l = l0 + w + 4 * i;
    Ag[(b * 256 + l) * 64 + f] = accA[i] + (float)l * wca;
    Bg[(b * 256 + l) * 64 + f] = accB[i] + (float)l * wcb + bias;
  }
}

// ---------------------------------------------------------------------------
// Kernel 2: pair loop. grid (256, 16) x 64 thr: one wave per block, one
// 16p x 16q tile per wave, 4096 independent workgroups (16/CU). No LDS,
// no barriers. B'-rows via quad-broadcast global ldf4 (L1/L2-resident),
// 1-ahead prefetch rotation. Epilogue: shfl-reduce over q (mm lanes) ->
// private Part slot per wave (no contention).
// ---------------------------------------------------------------------------
__global__ __launch_bounds__(64) void k_main(
    const float* __restrict__ Ag, const float* __restrict__ Bg,
    const float* __restrict__ Wg1, const float* __restrict__ bg1,
    const float* __restrict__ Wg2, const float* __restrict__ bg2,
    float* __restrict__ Part) {
  const int lane = threadIdx.x;         // 0..63
  const int mm = lane & 15;
  const int quad = lane >> 4;
  const int b = blockIdx.y;
  const int blk = blockIdx.x;           // 0..255
  const int p0 = (blk >> 4) * 16;       // 16 p-groups of 16 rows
  const int q0 = (blk & 15) * 16;       // 16 q-groups of 16 rows

  // ---- A rows pinned: A[q0+mm][f = kh*32 + quad*8 + j] ----
  const float* Arow = Ag + (b * 256 + q0 + mm) * 64;
  f4v af0 = ldf4(Arow + quad * 8);
  f4v af1 = ldf4(Arow + quad * 8 + 4);
  f4v af2 = ldf4(Arow + 32 + quad * 8);
  f4v af3 = ldf4(Arow + 36 + quad * 8);

  // ---- layer-1 weights, K32 A-operand: W1[gt*16+mm][kh*32+quad*8+j] ----
  s8v W1f[4][2];
  // ---- layer-2 weights, K16 A-operand: W2[ot*16+mm][gt*16+quad*4+i] ----
  s4v W2f[4][4];
  f4v c1i[4], c2i[4];
#pragma unroll
  for (int gt = 0; gt < 4; ++gt) {
    c1i[gt] = ldf4(bg1 + gt * 16 + quad * 4);
    c2i[gt] = ldf4(bg2 + gt * 16 + quad * 4);
#pragma unroll
    for (int kh = 0; kh < 2; ++kh) {
      const float* r1 = Wg1 + (gt * 16 + mm) * 64 + kh * 32 + quad * 8;
      W1f[gt][kh] = cvt8(ldf4(r1), ldf4(r1 + 4));
    }
#pragma unroll
    for (int kt = 0; kt < 4; ++kt) {
      const float* r2 = Wg2 + (gt * 16 + mm) * 64 + kt * 16 + quad * 4;
      W2f[gt][kt] = cvt4(ldf4(r2));
    }
  }
  // Pin loop-invariants in registers (defeat remat/sink).
#pragma unroll
  for (int gt = 0; gt < 4; ++gt) {
    KEEP(W1f[gt][0]); KEEP(W1f[gt][1]);
    KEEP(W2f[gt][0]); KEEP(W2f[gt][1]); KEEP(W2f[gt][2]); KEEP(W2f[gt][3]);
    KEEP(c1i[gt]); KEEP(c2i[gt]);
  }
  KEEP(af0); KEEP(af1); KEEP(af2); KEEP(af3);

  f4v cs[4] = {{0.f,0.f,0.f,0.f},{0.f,0.f,0.f,0.f},
               {0.f,0.f,0.f,0.f},{0.f,0.f,0.f,0.f}};

  // ---- B'-frag prefetch rotation (global quad-broadcast, L1/L2-hit) ----
  const float* Bbase = Bg + (b * 256 + p0) * 64;
  f4v bq0 = ldf4(Bbase + quad * 8);
  f4v bq1 = ldf4(Bbase + quad * 8 + 4);
  f4v bq2 = ldf4(Bbase + 32 + quad * 8);
  f4v bq3 = ldf4(Bbase + 36 + quad * 8);

  for (int ip = 0; ip < 16; ++ip) {
    const float* bn = Bbase + ((ip < 15) ? ip + 1 : 15) * 64;
    f4v bn0 = ldf4(bn + quad * 8);
    f4v bn1 = ldf4(bn + quad * 8 + 4);
    f4v bn2 = ldf4(bn + 32 + quad * 8);
    f4v bn3 = ldf4(bn + 36 + quad * 8);

    // ---- X fragment: X[q=mm][f] = relu(A+B'), K32 A/B-operand layout ----
    s8v x0 = cvt8(relu4(af0 + bq0), relu4(af1 + bq1));
    s8v x1 = cvt8(relu4(af2 + bq2), relu4(af3 + bq3));

    // ---- layer 1: k-outer, 4 independent acc chains ----
    f4v a1[4];
#pragma unroll
    for (int gt = 0; gt < 4; ++gt) a1[gt] = c1i[gt];
#pragma unroll
    for (int gt = 0; gt < 4; ++gt) a1[gt] = MFMA32(W1f[gt][0], x0, a1[gt]);
#pragma unroll
    for (int gt = 0; gt < 4; ++gt) a1[gt] = MFMA32(W1f[gt][1], x1, a1[gt]);
    s4v pk[4];
#pragma unroll
    for (int gt = 0; gt < 4; ++gt) pk[gt] = cvt4(relu4(a1[gt]));

    // ---- layer 2: k-outer, 4 independent acc chains ----
    f4v a2[4];
#pragma unroll
    for (int ot = 0; ot < 4; ++ot) a2[ot] = c2i[ot];
#pragma unroll
    for (int kt = 0; kt < 4; ++kt) {
#pragma unroll
      for (int ot = 0; ot < 4; ++ot) a2[ot] = MFMA16(W2f[ot][kt], pk[kt], a2[ot]);
    }
#pragma unroll
    for (int ot = 0; ot < 4; ++ot) cs[ot] += relu4(a2[ot]);
    // lane: o = ot*16+quad*4+r, q = mm

    bq0 = bn0; bq1 = bn1; bq2 = bn2; bq3 = bn3;
  }

  // ---- reduce over q (mm lanes, xor masks touch only mm bits) ----
#pragma unroll
  for (int ot = 0; ot < 4; ++ot) {
#pragma unroll
    for (int r = 0; r < 4; ++r) {
      float v = cs[ot][r];
      v += __shfl_xor(v, 1);
      v += __shfl_xor(v, 2);
      v += __shfl_xor(v, 4);
      v += __shfl_xor(v, 8);
      if (mm == 0)
        Part[(b * 256 + blk) * 64 + ot * 16 + quad * 4 + r] = v;  // private slot
    }
  }
}

// ---------------------------------------------------------------------------
// Kernel 3: reduce 256 partials per (b,o), then f-network. grid 16 x 256.
// ---------------------------------------------------------------------------
__global__ __launch_bounds__(256) void k_final(
    const float* __restrict__ Part, const float* __restrict__ Wp,
    const float* __restrict__ bp, const float* __restrict__ Wo,
    const float* __restrict__ bo, float* __restrict__ out) {
  __shared__ float red[4][64];
  __shared__ float sv[64], tv[64];
  const int b = blockIdx.x, t = threadIdx.x;
  const int o = t & 63, jw = t >> 6;
  const float* Pb = Part + b * 256 * 64;
  float s = 0.f;
#pragma unroll
  for (int j = 0; j < 64; ++j) s += Pb[(jw * 64 + j) * 64 + o];  // coalesced
  red[jw][o] = s;
  __syncthreads();
  if (t < 64) sv[t] = red[0][t] + red[1][t] + red[2][t] + red[3][t];
  __syncthreads();
  if (t < 64) {
    float acc = bp[t];
#pragma unroll
    for (int g4 = 0; g4 < 16; ++g4) {
      f4v wv = ldf4(Wp + t * 64 + g4 * 4);
      f4v xv = ldf4(sv + g4 * 4);
      acc += wv[0] * xv[0] + wv[1] * xv[1] + wv[2] * xv[2] + wv[3] * xv[3];
    }
    tv[t] = fmaxf(acc, 0.f);
  }
  __syncthreads();
  if (t < 64) {
    float o2 = bo[t];
#pragma unroll
    for (int g4 = 0; g4 < 16; ++g4) {
      f4v wv = ldf4(Wo + t * 64 + g4 * 4);
      f4v xv = ldf4(tv + g4 * 4);
      o2 += wv[0] * xv[0] + wv[1] * xv[1] + wv[2] * xv[2] + wv[3] * xv[3];
    }
    out[b * 64 + t] = o2;
  }
}

// ---------------------------------------------------------------------------
extern "C" void kernel_launch(void* const* d_in, const int* in_sizes, int n_in,
                              void* d_out, int out_size, void* d_ws, size_t ws_size,
                              hipStream_t stream) {
  const float* x   = (const float*)d_in[0];
  const float* Wg0 = (const float*)d_in[1];
  const float* bg0 = (const float*)d_in[2];
  const float* Wg1 = (const float*)d_in[3];
  const float* bg1 = (const float*)d_in[4];
  const float* Wg2 = (const float*)d_in[5];
  const float* bg2 = (const float*)d_in[6];
  const float* Wp  = (const float*)d_in[7];
  const float* bp  = (const float*)d_in[8];
  const float* Wo  = (const float*)d_in[9];
  const float* bo  = (const float*)d_in[10];
  float* out = (float*)d_out;

  float* Ag   = (float*)d_ws;            // [16][256][64] fp32 = 1 MB
  float* Bg   = Ag + 16 * 256 * 64;      // [16][256][64] fp32 = 1 MB
  float* Part = Bg + 16 * 256 * 64;      // [16][256][64] fp32 = 4 MB

  k_pre<<<256, 256, 0, stream>>>(x, Wg0, bg0, Ag, Bg);
  k_main<<<dim3(256, 16), 64, 0, stream>>>(Ag, Bg, Wg1, bg1, Wg2, bg2, Part);
  k_final<<<16, 256, 0, stream>>>(Part, Wp, bp, Wo, bo, out);
}

// Round 6
// 117.945 us; speedup vs baseline: 1.1133x; 1.1133x over previous
//
#include <hip/hip_runtime.h>

// ---------------------------------------------------------------------------
// BatchRelationalModule: b=16, c=64, L=256, F=64
// Round 12: CUT VALU + 1-STAGE SOFTWARE PIPELINE (base = verified r9/41.4us).
// r11 evidence: occupancy pinned ~17.5% across 512x4w / 1024x4w / 4096x1w
// grids => wave-count axis dead; global-B variant slower (longer dep chain).
// r9 accounting now closes: VALU issue = 36% x 41.4 = 14.9us == recounted
// ~275 VALU/iter (incl. 32 acc-init movs + 32 rotation movs + 48 cvt/pack),
// MFMA 9.4us, stall 17us. This round:
//  (1) no acc-init movs: c1i/c2i passed directly as C of first MFMA (D!=C ok)
//  (2) no bq=bn rotation: read B-frags per-iter, compiler hoists ds_reads
//  (3) 1-stage pipeline: X+layer1 of p+1 runs against layer2+accum of p
//      (two independent streams per body; +8 VGPR for pk carry only —
//       NOT the r10 full-duplication that blew regalloc)
// Predict: k_main 41.4 -> 27-33us, VALUBusy -> ~50%, MfmaUtil -> ~32%,
// VGPR ~110-130, FETCH ~3.2MB (no spill), dur_us -> ~100-107.
// ---------------------------------------------------------------------------

typedef short s8v __attribute__((ext_vector_type(8)));   // 8 x bf16 (4 VGPR)
typedef short s4v __attribute__((ext_vector_type(4)));   // 4 x bf16 (2 VGPR)
typedef float f4v __attribute__((ext_vector_type(4)));   // 4 x f32  (4 VGPR)

#define KEEP(x) asm volatile("" : "+v"(x))   // opaque: forbids remat/sink

#define MFMA16(a, b, c) __builtin_amdgcn_mfma_f32_16x16x16bf16_1k(a, b, c, 0, 0, 0)
#define MFMA32(a, b, c) __builtin_amdgcn_mfma_f32_16x16x32_bf16(a, b, c, 0, 0, 0)

__device__ __forceinline__ short bfr(float v) {
  return __builtin_bit_cast(short, (__bf16)v);           // fp32 -> bf16 (RNE)
}
__device__ __forceinline__ f4v relu4(f4v v) {
  f4v z = {0.f, 0.f, 0.f, 0.f};
  return __builtin_elementwise_max(v, z);
}
__device__ __forceinline__ s8v cvt8(f4v a, f4v b) {
  s8v r;
  r[0] = bfr(a[0]); r[1] = bfr(a[1]); r[2] = bfr(a[2]); r[3] = bfr(a[3]);
  r[4] = bfr(b[0]); r[5] = bfr(b[1]); r[6] = bfr(b[2]); r[7] = bfr(b[3]);
  return r;
}
__device__ __forceinline__ s4v cvt4(f4v a) {
  s4v r;
  r[0] = bfr(a[0]); r[1] = bfr(a[1]); r[2] = bfr(a[2]); r[3] = bfr(a[3]);
  return r;
}
__device__ __forceinline__ f4v ldf4(const float* p) {
  return *(const f4v*)p;
}

// ---------------------------------------------------------------------------
// Kernel 1: precompute A and B' (fp32). Unchanged (verified).
// ---------------------------------------------------------------------------
__global__ __launch_bounds__(256) void k_pre(
    const float* __restrict__ x, const float* __restrict__ Wg0,
    const float* __restrict__ bg0, float* __restrict__ Ag,
    float* __restrict__ Bg) {
  __shared__ float ws[64 * 131];
  __shared__ float xs[64 * 17];

  const int t = threadIdx.x;
  const int b = blockIdx.x >> 4;
  const int l0 = (blockIdx.x & 15) * 16;

  for (int i = t; i < 64 * 130; i += 256) {
    int f = i / 130, d = i - f * 130;
    ws[f * 131 + d] = Wg0[i];
  }
  for (int i = t; i < 64 * 16; i += 256) {
    int ch = i >> 4, li = i & 15;
    xs[ch * 17 + li] = x[b * 16384 + ch * 256 + l0 + li];
  }
  __syncthreads();

  const int f = t & 63;
  const int w = t >> 6;
  float accA[4] = {0.f, 0.f, 0.f, 0.f};
  float accB[4] = {0.f, 0.f, 0.f, 0.f};
  for (int d = 0; d < 64; ++d) {
    float wa = ws[f * 131 + d];
    float wb = ws[f * 131 + 65 + d];
#pragma unroll
    for (int i = 0; i < 4; ++i) {
      float xv = xs[d * 17 + w + 4 * i];
      accA[i] += xv * wa;
      accB[i] += xv * wb;
    }
  }
  const float wca = ws[f * 131 + 64];
  const float wcb = ws[f * 131 + 129];
  const float bias = bg0[f];
#pragma unroll
  for (int i = 0; i < 4; ++i) {
    int l = l0 + w + 4 * i;
    Ag[(b * 256 + l) * 64 + f] = accA[i] + (float)l * wca;
    Bg[(b * 256 + l) * 64 + f] = accB[i] + (float)l * wcb + bias;
  }
}

// ---------------------------------------------------------------------------
// Kernel 2: pair loop, software-pipelined. grid (64, 16) x 256 thr.
// 16 p-rows per block. Loop body holds two independent streams:
//   stream A: B'-frag(ip) -> X(ip) -> layer1(ip) -> a1
//   stream B: layer2(pk from ip-1) -> cs accumulate
// joined only by the pk handoff at the bottom. launch_bounds (256,2):
// do NOT cap allocator (r8 lesson).
// ---------------------------------------------------------------------------
__global__ __launch_bounds__(256, 2) void k_main(
    const float* __restrict__ Ag, const float* __restrict__ Bg,
    const float* __restrict__ Wg1, const float* __restrict__ bg1,
    const float* __restrict__ Wg2, const float* __restrict__ bg2,
    float* __restrict__ Part) {
  __shared__ __align__(16) float Bs[16 * 64];   // 4 KB
  __shared__ float WaveS[4 * 64];               // 1 KB

  const int t = threadIdx.x;
  const int wid = t >> 6;
  const int lane = t & 63;
  const int mm = lane & 15;
  const int quad = lane >> 4;
  const int b = blockIdx.y;
  const int blkx = blockIdx.x;          // 0..63
  const int qq = blkx & 3;
  const int p0 = (blkx >> 2) * 16;      // 16 p-groups of 16 rows
  const int q0 = (qq * 4 + wid) * 16;

  // ---- stage B'[16 rows] (4 KB) into LDS, coalesced dwordx4 ----
  {
    const f4v* Bb4 = (const f4v*)(Bg + (b * 256 + p0) * 64);
    ((f4v*)Bs)[t] = Bb4[t];
  }

  // ---- A rows pinned: A[q0+mm][f = kh*32 + quad*8 + j] ----
  const float* Arow = Ag + (b * 256 + q0 + mm) * 64;
  f4v af0 = ldf4(Arow + quad * 8);
  f4v af1 = ldf4(Arow + quad * 8 + 4);
  f4v af2 = ldf4(Arow + 32 + quad * 8);
  f4v af3 = ldf4(Arow + 36 + quad * 8);

  // ---- layer-1 weights, K32 A-operand: W1[gt*16+mm][kh*32+quad*8+j] ----
  s8v W1f[4][2];
  // ---- layer-2 weights, K16 A-operand: W2[ot*16+mm][gt*16+quad*4+i] ----
  s4v W2f[4][4];
  f4v c1i[4], c2i[4];
#pragma unroll
  for (int gt = 0; gt < 4; ++gt) {
    c1i[gt] = ldf4(bg1 + gt * 16 + quad * 4);
    c2i[gt] = ldf4(bg2 + gt * 16 + quad * 4);
#pragma unroll
    for (int kh = 0; kh < 2; ++kh) {
      const float* r1 = Wg1 + (gt * 16 + mm) * 64 + kh * 32 + quad * 8;
      W1f[gt][kh] = cvt8(ldf4(r1), ldf4(r1 + 4));
    }
#pragma unroll
    for (int kt = 0; kt < 4; ++kt) {
      const float* r2 = Wg2 + (gt * 16 + mm) * 64 + kt * 16 + quad * 4;
      W2f[gt][kt] = cvt4(ldf4(r2));
    }
  }
  // Pin loop-invariants in registers (defeat remat/sink). Same KEEP set
  // that compiled clean at VGPR=92 in r9.
#pragma unroll
  for (int gt = 0; gt < 4; ++gt) {
    KEEP(W1f[gt][0]); KEEP(W1f[gt][1]);
    KEEP(W2f[gt][0]); KEEP(W2f[gt][1]); KEEP(W2f[gt][2]); KEEP(W2f[gt][3]);
    KEEP(c1i[gt]); KEEP(c2i[gt]);
  }
  KEEP(af0); KEEP(af1); KEEP(af2); KEEP(af3);

  __syncthreads();   // Bs staged

  f4v cs[4] = {{0.f,0.f,0.f,0.f},{0.f,0.f,0.f,0.f},
               {0.f,0.f,0.f,0.f},{0.f,0.f,0.f,0.f}};

  // ---- pipeline prologue: X(0) -> layer1(0) -> pk ----
  s4v pk[4];
  {
    const float* bp_ = Bs;
    f4v b0 = ldf4(bp_ + quad * 8);
    f4v b1 = ldf4(bp_ + quad * 8 + 4);
    f4v b2 = ldf4(bp_ + 32 + quad * 8);
    f4v b3 = ldf4(bp_ + 36 + quad * 8);
    s8v x0 = cvt8(relu4(af0 + b0), relu4(af1 + b1));
    s8v x1 = cvt8(relu4(af2 + b2), relu4(af3 + b3));
#pragma unroll
    for (int gt = 0; gt < 4; ++gt) {
      // C-operand = c1i directly: no acc-init movs (D != C is legal)
      f4v a1 = MFMA32(W1f[gt][1], x1, MFMA32(W1f[gt][0], x0, c1i[gt]));
      pk[gt] = cvt4(relu4(a1));
    }
  }

  // ---- steady state: layer1(ip) || layer2(ip-1) ----
  for (int ip = 1; ip < 16; ++ip) {
    // stream A: next p
    const float* bp_ = Bs + ip * 64;
    f4v b0 = ldf4(bp_ + quad * 8);
    f4v b1 = ldf4(bp_ + quad * 8 + 4);
    f4v b2 = ldf4(bp_ + 32 + quad * 8);
    f4v b3 = ldf4(bp_ + 36 + quad * 8);
    s8v x0 = cvt8(relu4(af0 + b0), relu4(af1 + b1));
    s8v x1 = cvt8(relu4(af2 + b2), relu4(af3 + b3));
    f4v a1[4];
#pragma unroll
    for (int gt = 0; gt < 4; ++gt)
      a1[gt] = MFMA32(W1f[gt][1], x1, MFMA32(W1f[gt][0], x0, c1i[gt]));

    // stream B: current p's layer 2 (independent of stream A)
#pragma unroll
    for (int ot = 0; ot < 4; ++ot) {
      f4v a2 = MFMA16(W2f[ot][3], pk[3],
               MFMA16(W2f[ot][2], pk[2],
               MFMA16(W2f[ot][1], pk[1],
               MFMA16(W2f[ot][0], pk[0], c2i[ot]))));
      cs[ot] += relu4(a2);   // lane: o = ot*16+quad*4+r, q = mm
    }

    // handoff
#pragma unroll
    for (int gt = 0; gt < 4; ++gt) pk[gt] = cvt4(relu4(a1[gt]));
  }

  // ---- pipeline epilogue: layer2 on last pk ----
#pragma unroll
  for (int ot = 0; ot < 4; ++ot) {
    f4v a2 = MFMA16(W2f[ot][3], pk[3],
             MFMA16(W2f[ot][2], pk[2],
             MFMA16(W2f[ot][1], pk[1],
             MFMA16(W2f[ot][0], pk[0], c2i[ot]))));
    cs[ot] += relu4(a2);
  }

  // ---- reduce over q (mm lanes) -> per-wave LDS slice (NO atomics) ----
#pragma unroll
  for (int ot = 0; ot < 4; ++ot) {
#pragma unroll
    for (int r = 0; r < 4; ++r) {
      float v = cs[ot][r];
      v += __shfl_xor(v, 1);
      v += __shfl_xor(v, 2);
      v += __shfl_xor(v, 4);
      v += __shfl_xor(v, 8);
      if (mm == 0) WaveS[wid * 64 + ot * 16 + quad * 4 + r] = v;
    }
  }
  __syncthreads();
  if (t < 64) {
    float s = WaveS[t] + WaveS[64 + t] + WaveS[128 + t] + WaveS[192 + t];
    Part[(b * 64 + blkx) * 64 + t] = s;   // distinct slot, no contention
  }
}

// ---------------------------------------------------------------------------
// Kernel 3: reduce 64 partials per (b,o), then f-network. grid 16 x 256.
// ---------------------------------------------------------------------------
__global__ __launch_bounds__(256) void k_final(
    const float* __restrict__ Part, const float* __restrict__ Wp,
    const float* __restrict__ bp, const float* __restrict__ Wo,
    const float* __restrict__ bo, float* __restrict__ out) {
  __shared__ float red[4][64];
  __shared__ float sv[64], tv[64];
  const int b = blockIdx.x, t = threadIdx.x;
  const int o = t & 63, jw = t >> 6;
  const float* Pb = Part + b * 64 * 64;
  float s = 0.f;
#pragma unroll
  for (int j = 0; j < 16; ++j) s += Pb[(jw * 16 + j) * 64 + o];  // coalesced
  red[jw][o] = s;
  __syncthreads();
  if (t < 64) sv[t] = red[0][t] + red[1][t] + red[2][t] + red[3][t];
  __syncthreads();
  if (t < 64) {
    float acc = bp[t];
#pragma unroll
    for (int g4 = 0; g4 < 16; ++g4) {
      f4v wv = ldf4(Wp + t * 64 + g4 * 4);
      f4v xv = ldf4(sv + g4 * 4);
      acc += wv[0] * xv[0] + wv[1] * xv[1] + wv[2] * xv[2] + wv[3] * xv[3];
    }
    tv[t] = fmaxf(acc, 0.f);
  }
  __syncthreads();
  if (t < 64) {
    float o2 = bo[t];
#pragma unroll
    for (int g4 = 0; g4 < 16; ++g4) {
      f4v wv = ldf4(Wo + t * 64 + g4 * 4);
      f4v xv = ldf4(tv + g4 * 4);
      o2 += wv[0] * xv[0] + wv[1] * xv[1] + wv[2] * xv[2] + wv[3] * xv[3];
    }
    out[b * 64 + t] = o2;
  }
}

// ---------------------------------------------------------------------------
extern "C" void kernel_launch(void* const* d_in, const int* in_sizes, int n_in,
                              void* d_out, int out_size, void* d_ws, size_t ws_size,
                              hipStream_t stream) {
  const float* x   = (const float*)d_in[0];
  const float* Wg0 = (const float*)d_in[1];
  const float* bg0 = (const float*)d_in[2];
  const float* Wg1 = (const float*)d_in[3];
  const float* bg1 = (const float*)d_in[4];
  const float* Wg2 = (const float*)d_in[5];
  const float* bg2 = (const float*)d_in[6];
  const float* Wp  = (const float*)d_in[7];
  const float* bp  = (const float*)d_in[8];
  const float* Wo  = (const float*)d_in[9];
  const float* bo  = (const float*)d_in[10];
  float* out = (float*)d_out;

  float* Ag   = (float*)d_ws;            // [16][256][64] fp32 = 1 MB
  float* Bg   = Ag + 16 * 256 * 64;      // [16][256][64] fp32 = 1 MB
  float* Part = Bg + 16 * 256 * 64;      // [16][64][64] fp32 = 256 KB

  k_pre<<<256, 256, 0, stream>>>(x, Wg0, bg0, Ag, Bg);
  k_main<<<dim3(64, 16), 256, 0, stream>>>(Ag, Bg, Wg1, bg1, Wg2, bg2, Part);
  k_final<<<16, 256, 0, stream>>>(Part, Wp, bp, Wo, bo, out);
}